// Round 1
// baseline (522.059 us; speedup 1.0000x reference)
//
#include <hip/hip_runtime.h>
#include <hip/hip_bf16.h>

// Problem constants (fixed by setup_inputs)
#define B_    2
#define H_    32
#define KVH_  8
#define T_    4096
#define C_    4096
#define D_    128
#define W_    512
#define KTOP  1024
#define TOUT  (T_ + KTOP)      // 5120
#define QB    64               // queries per block
#define TB    64               // keys per tile
#define NQBLK (W_/QB)          // 8
#define NPART (H_*NQBLK)       // 256 partial slices per batch
#define SCALE 0.08838834764831845f   // 128^-0.5

typedef __attribute__((ext_vector_type(8))) _Float16 half8;
typedef __attribute__((ext_vector_type(4))) _Float16 half4;
typedef __attribute__((ext_vector_type(4))) float f32x4;

// ---------------------------------------------------------------------------
// Kernel 1: per-block partial importance.
// Block = (qb, h, b): 64 queries x full key range, 4 waves (16 q each).
// Split-f16 MFMA: s = qh*kh + qh*kl + ql*kh  (error ~2^-24 rel -> safe topk).
// Two passes: pass1 online (m,l) per query; pass2 accumulate sum_q w into LDS
// bins, serialized across waves for determinism. No atomics.
// ---------------------------------------------------------------------------
__global__ __launch_bounds__(256) void imp_partial_kernel(
    const float* __restrict__ q_w, const float* __restrict__ km,
    float* __restrict__ partial)
{
    __shared__ __align__(16) _Float16 sKh[TB*D_];
    __shared__ __align__(16) _Float16 sKl[TB*D_];
    __shared__ float sP[T_];

    const int tid  = threadIdx.x;
    const int wid  = tid >> 6;
    const int lane = tid & 63;
    const int lg   = lane >> 4;   // k-group 0..3
    const int li   = lane & 15;   // m/n index
    const int qb = blockIdx.x, h = blockIdx.y, b = blockIdx.z;

    for (int i = tid; i < T_; i += 256) sP[i] = 0.f;

    // ---- load Q fragments into registers (hi/lo f16 split) ----
    const int qrow = qb*QB + wid*16 + li;
    const float* qp = q_w + (((size_t)b*H_ + h)*W_ + qrow)*D_;
    half8 qh[4], ql[4];
#pragma unroll
    for (int ks = 0; ks < 4; ++ks) {
        const float* p = qp + ks*32 + lg*8;
        float4 v0 = *(const float4*)p;
        float4 v1 = *(const float4*)(p+4);
        float f[8] = {v0.x,v0.y,v0.z,v0.w,v1.x,v1.y,v1.z,v1.w};
#pragma unroll
        for (int e = 0; e < 8; ++e) {
            _Float16 hi = (_Float16)f[e];
            _Float16 lo = (_Float16)(f[e] - (float)hi);
            qh[ks][e] = hi; ql[ks][e] = lo;
        }
    }

    const float* kbase = km + (((size_t)b*KVH_ + (h>>2))*T_)*D_;

    float m[4], l[4];
#pragma unroll
    for (int j = 0; j < 4; ++j) { m[j] = -1e30f; l[j] = 0.f; }

#define STAGE_K(tt)                                                         \
    {                                                                       \
        const int r = tid >> 2, pp = tid & 3;                               \
        const float* kp = kbase + (size_t)((tt)*TB + r)*D_ + pp*32;         \
        const int xr = (r & 7) << 3;                                        \
        _Pragma("unroll")                                                   \
        for (int i = 0; i < 8; ++i) {                                       \
            int d = pp*32 + i*4;                                            \
            float4 v = *(const float4*)(kp + i*4);                          \
            _Float16 h0=(_Float16)v.x, h1=(_Float16)v.y,                    \
                     h2=(_Float16)v.z, h3=(_Float16)v.w;                    \
            _Float16 l0=(_Float16)(v.x-(float)h0), l1=(_Float16)(v.y-(float)h1),\
                     l2=(_Float16)(v.z-(float)h2), l3=(_Float16)(v.w-(float)h3);\
            *(half4*)&sKh[r*D_ + (d^xr)] = (half4){h0,h1,h2,h3};            \
            *(half4*)&sKl[r*D_ + (d^xr)] = (half4){l0,l1,l2,l3};            \
        }                                                                   \
    }

#define COMPUTE_S(acc)                                                      \
    {                                                                       \
        _Pragma("unroll")                                                   \
        for (int n = 0; n < 4; ++n) acc[n] = (f32x4){0.f,0.f,0.f,0.f};      \
        _Pragma("unroll")                                                   \
        for (int ks = 0; ks < 4; ++ks) {                                    \
            _Pragma("unroll")                                               \
            for (int n = 0; n < 4; ++n) {                                   \
                int r = n*16 + li;                                          \
                int off = r*D_ + ((ks*32 + lg*8) ^ ((r & 7) << 3));         \
                half8 bh = *(const half8*)&sKh[off];                        \
                half8 bl = *(const half8*)&sKl[off];                        \
                acc[n] = __builtin_amdgcn_mfma_f32_16x16x32_f16(qh[ks], bh, acc[n], 0,0,0); \
                acc[n] = __builtin_amdgcn_mfma_f32_16x16x32_f16(ql[ks], bh, acc[n], 0,0,0); \
                acc[n] = __builtin_amdgcn_mfma_f32_16x16x32_f16(qh[ks], bl, acc[n], 0,0,0); \
            }                                                               \
        }                                                                   \
    }

    // ---- pass 1: online row max + sumexp ----
    for (int tt = 0; tt < T_/TB; ++tt) {
        STAGE_K(tt);
        __syncthreads();
        f32x4 acc[4];
        COMPUTE_S(acc);
#pragma unroll
        for (int j = 0; j < 4; ++j) {
            float s0 = acc[0][j]*SCALE, s1 = acc[1][j]*SCALE;
            float s2 = acc[2][j]*SCALE, s3 = acc[3][j]*SCALE;
            float tmax = fmaxf(fmaxf(s0,s1), fmaxf(s2,s3));
            tmax = fmaxf(tmax, __shfl_xor(tmax, 1));
            tmax = fmaxf(tmax, __shfl_xor(tmax, 2));
            tmax = fmaxf(tmax, __shfl_xor(tmax, 4));
            tmax = fmaxf(tmax, __shfl_xor(tmax, 8));
            float mn = fmaxf(m[j], tmax);
            float e = __expf(s0-mn) + __expf(s1-mn) + __expf(s2-mn) + __expf(s3-mn);
            e += __shfl_xor(e, 1); e += __shfl_xor(e, 2);
            e += __shfl_xor(e, 4); e += __shfl_xor(e, 8);
            l[j] = l[j]*__expf(m[j]-mn) + e;
            m[j] = mn;
        }
        __syncthreads();
    }

    float rl[4];
#pragma unroll
    for (int j = 0; j < 4; ++j) rl[j] = 1.0f / l[j];

    // ---- pass 2: accumulate sum_q weights into key bins ----
    for (int tt = 0; tt < T_/TB; ++tt) {
        STAGE_K(tt);
        __syncthreads();
        f32x4 acc[4];
        COMPUTE_S(acc);
        float v[4];
#pragma unroll
        for (int n = 0; n < 4; ++n) {
            float x = 0.f;
#pragma unroll
            for (int j = 0; j < 4; ++j)
                x += __expf(acc[n][j]*SCALE - m[j]) * rl[j];
            x += __shfl_xor(x, 16);
            x += __shfl_xor(x, 32);
            v[n] = x;
        }
        // deterministic cross-wave accumulation (fixed order, no atomics)
        for (int w = 0; w < 4; ++w) {
            if (wid == w && lane < 16) {
#pragma unroll
                for (int n = 0; n < 4; ++n)
                    sP[tt*TB + n*16 + lane] += v[n];
            }
            __syncthreads();
        }
    }

    const size_t po = ((size_t)(h*NQBLK + qb)*B_ + b)*T_;
    for (int i = tid; i < T_/4; i += 256)
        ((f32x4*)(partial + po))[i] = ((const f32x4*)sP)[i];
}

// ---------------------------------------------------------------------------
// Kernel 2: deterministic fixed-order reduce over 256 partial slices, /H.
// ---------------------------------------------------------------------------
__global__ __launch_bounds__(256) void imp_reduce_kernel(
    const float* __restrict__ partial, float* __restrict__ imp)
{
    int gid = blockIdx.x*256 + threadIdx.x;   // 8192 = B*T
    int b = gid >> 12, t = gid & (T_-1);
    float s = 0.f;
    for (int i = 0; i < NPART; ++i)
        s += partial[((size_t)(i*B_ + b))*T_ + t];
    imp[gid] = s * (1.0f/H_);
}

// ---------------------------------------------------------------------------
// Kernel 3: per-batch bitonic top-k (desc, idx-asc tiebreak) + prefix scan.
// ---------------------------------------------------------------------------
__global__ __launch_bounds__(1024) void topk_kernel(
    const float* __restrict__ imp, int* __restrict__ mask, int* __restrict__ start)
{
    __shared__ float sv[T_];
    __shared__ int   si[T_];
    __shared__ int   sm[T_];
    __shared__ int   sa[1024], sb[1024];
    const int tid = threadIdx.x, b = blockIdx.x;

    for (int i = tid; i < T_; i += 1024) { sv[i] = imp[b*T_+i]; si[i] = i; }
    __syncthreads();

    for (int k = 2; k <= T_; k <<= 1) {
        for (int j = k >> 1; j > 0; j >>= 1) {
            for (int i = tid; i < T_; i += 1024) {
                int ix = i ^ j;
                if (ix > i) {
                    float av = sv[i], bv = sv[ix];
                    int   ai = si[i], bi = si[ix];
                    bool aFirst = (av > bv) || (av == bv && ai < bi);
                    bool desc = ((i & k) == 0);
                    if (desc ? !aFirst : aFirst) {
                        sv[i] = bv; sv[ix] = av; si[i] = bi; si[ix] = ai;
                    }
                }
            }
            __syncthreads();
        }
    }

    for (int i = tid; i < T_; i += 1024) sm[i] = 0;
    __syncthreads();
    if (tid < KTOP) sm[si[tid]] = 1;
    __syncthreads();

    int i0 = 4*tid;
    int m0 = sm[i0], m1 = sm[i0+1], m2 = sm[i0+2], m3 = sm[i0+3];
    int s4 = m0+m1+m2+m3;
    sa[tid] = s4;
    __syncthreads();
    int *src = sa, *dst = sb;
    for (int off = 1; off < 1024; off <<= 1) {
        int v = src[tid];
        if (tid >= off) v += src[tid-off];
        dst[tid] = v;
        __syncthreads();
        int* tmp = src; src = dst; dst = tmp;
    }
    int excl = src[tid] - s4;
    start[b*T_+i0+0] = i0+0 + excl;
    start[b*T_+i0+1] = i0+1 + excl + m0;
    start[b*T_+i0+2] = i0+2 + excl + m0+m1;
    start[b*T_+i0+3] = i0+3 + excl + m0+m1+m2;
    mask[b*T_+i0+0] = m0; mask[b*T_+i0+1] = m1;
    mask[b*T_+i0+2] = m2; mask[b*T_+i0+3] = m3;
}

// ---------------------------------------------------------------------------
// Kernel 4: scatter-copy rows. Every output row written exactly once.
// ---------------------------------------------------------------------------
__global__ __launch_bounds__(256) void scatter_kernel(
    const float* __restrict__ x_m, const float* __restrict__ xm_cmp,
    const int* __restrict__ mask, const int* __restrict__ start,
    float* __restrict__ out)
{
    const int t = blockIdx.x, b = blockIdx.y, tid = threadIdx.x;
    const int mk = mask[b*T_+t];
    const int st = start[b*T_+t];
    const float* s1 = mk ? (x_m + ((size_t)b*2*T_ + 2*t)*C_)
                         : (xm_cmp + ((size_t)b*T_ + t)*C_);
    float4* d1 = (float4*)(out + ((size_t)b*TOUT + st)*C_);
    const float4* s1v = (const float4*)s1;
    for (int i = tid; i < C_/4; i += 256) d1[i] = s1v[i];
    if (mk) {
        const float4* s2v = (const float4*)(x_m + ((size_t)b*2*T_ + 2*t+1)*C_);
        float4* d2 = d1 + C_/4;
        for (int i = tid; i < C_/4; i += 256) d2[i] = s2v[i];
    }
}

extern "C" void kernel_launch(void* const* d_in, const int* in_sizes, int n_in,
                              void* d_out, int out_size, void* d_ws, size_t ws_size,
                              hipStream_t stream)
{
    (void)in_sizes; (void)n_in; (void)out_size; (void)ws_size;
    const float* x_m    = (const float*)d_in[0];
    const float* xm_cmp = (const float*)d_in[1];
    const float* q_w    = (const float*)d_in[2];
    const float* km     = (const float*)d_in[3];
    float* out = (float*)d_out;

    char* ws = (char*)d_ws;
    float* partial = (float*)ws;                                  // 8,388,608 B
    float* imp     = (float*)(ws + (size_t)NPART*B_*T_*4);        // 32 KB
    int*   mask    = (int*)  (ws + (size_t)NPART*B_*T_*4 + 32768);
    int*   start   = (int*)  (ws + (size_t)NPART*B_*T_*4 + 65536);

    imp_partial_kernel<<<dim3(NQBLK, H_, B_), dim3(256), 0, stream>>>(q_w, km, partial);
    imp_reduce_kernel<<<dim3((B_*T_)/256), dim3(256), 0, stream>>>(partial, imp);
    topk_kernel<<<dim3(B_), dim3(1024), 0, stream>>>(imp, mask, start);
    scatter_kernel<<<dim3(T_, B_), dim3(256), 0, stream>>>(x_m, xm_cmp, mask, start, out);
}

// Round 2
// 351.880 us; speedup vs baseline: 1.4836x; 1.4836x over previous
//
#include <hip/hip_runtime.h>
#include <hip/hip_bf16.h>

// Problem constants (fixed by setup_inputs)
#define B_    2
#define H_    32
#define KVH_  8
#define T_    4096
#define C_    4096
#define D_    128
#define W_    512
#define KTOP  1024
#define TOUT  (T_ + KTOP)      // 5120
#define QB    128              // queries per block (8 waves x 16)
#define NQB   (W_/QB)          // 4
#define NKS   4                // key-range splits
#define TB    64               // keys per tile
#define NTT   (T_/(TB*NKS))    // 16 tiles per ks slice
#define NPART (H_*NQB)         // 128 partial slices per batch
#define SCALE 0.08838834764831845f   // 128^-0.5

typedef __attribute__((ext_vector_type(8))) _Float16 half8;
typedef __attribute__((ext_vector_type(4))) float f32x4;

__device__ __forceinline__ void gload16(const void* g, void* l) {
    __builtin_amdgcn_global_load_lds(
        (const __attribute__((address_space(1))) void*)g,
        (__attribute__((address_space(3))) void*)l, 16, 0, 0);
}

// ---------------------------------------------------------------------------
// Kernel 0: convert km (f32) -> split f16 hi/lo, pre-swizzled tile layout.
// Tile layout per (b,kvh): [tile=t/64][r=t%64][128 cols], col d stored at
// d ^ ((r&7)<<3)  (element-granule XOR swizzle for conflict-managed b128 reads)
// ---------------------------------------------------------------------------
__global__ __launch_bounds__(256) void convert_k_kernel(
    const float* __restrict__ km, _Float16* __restrict__ Khw,
    _Float16* __restrict__ Klw)
{
    int g = blockIdx.x*256 + threadIdx.x;     // granule id (8 elements)
    size_t e = (size_t)g*8;
    int d0 = (int)(e & 127);
    size_t row = e >> 7;                      // bk*T + t
    int t = (int)(row & (T_-1));
    size_t bk = row >> 12;
    int r = t & 63, tt = t >> 6;
    size_t off = (bk<<19) + (size_t)tt*(TB*D_) + (size_t)r*D_ + (d0 ^ ((r&7)<<3));
    float4 v0 = *(const float4*)(km + e);
    float4 v1 = *(const float4*)(km + e + 4);
    float f[8] = {v0.x,v0.y,v0.z,v0.w,v1.x,v1.y,v1.z,v1.w};
    half8 hh, hl;
#pragma unroll
    for (int i = 0; i < 8; ++i) {
        _Float16 hi = (_Float16)f[i];
        hh[i] = hi;
        hl[i] = (_Float16)(f[i] - (float)hi);
    }
    *(half8*)&Khw[off] = hh;
    *(half8*)&Klw[off] = hl;
}

// ---- shared staging / compute macros (used by lsum + bins kernels) --------
// 512 threads: per tile, per f16 array: 1024 granules = 16 wave-issues.
#define STAGE(tt)                                                           \
    {                                                                       \
        const _Float16* gh_ = Khw + kvoff + ((size_t)(kt0+(tt)))*(TB*D_) + (size_t)tid*8; \
        const _Float16* gl_ = Klw + kvoff + ((size_t)(kt0+(tt)))*(TB*D_) + (size_t)tid*8; \
        gload16(gh_,        sKh + wid*512);                                 \
        gload16(gh_ + 4096, sKh + 4096 + wid*512);                          \
        gload16(gl_,        sKl + wid*512);                                 \
        gload16(gl_ + 4096, sKl + 4096 + wid*512);                          \
    }

#define COMPUTE_S(acc)                                                      \
    {                                                                       \
        _Pragma("unroll")                                                   \
        for (int n = 0; n < 4; ++n) acc[n] = (f32x4){0.f,0.f,0.f,0.f};      \
        _Pragma("unroll")                                                   \
        for (int ks2 = 0; ks2 < 4; ++ks2) {                                 \
            _Pragma("unroll")                                               \
            for (int n = 0; n < 4; ++n) {                                   \
                int r = n*16 + li;                                          \
                int off = r*D_ + ((ks2*32 + lg*8) ^ ((r & 7) << 3));        \
                half8 bh = *(const half8*)&sKh[off];                        \
                half8 bl = *(const half8*)&sKl[off];                        \
                acc[n] = __builtin_amdgcn_mfma_f32_16x16x32_f16(qh[ks2], bh, acc[n], 0,0,0); \
                acc[n] = __builtin_amdgcn_mfma_f32_16x16x32_f16(ql[ks2], bh, acc[n], 0,0,0); \
                acc[n] = __builtin_amdgcn_mfma_f32_16x16x32_f16(qh[ks2], bl, acc[n], 0,0,0); \
            }                                                               \
        }                                                                   \
    }

#define LOAD_Q()                                                            \
    const float* qp = q_w + (((size_t)b*H_ + h)*W_ + qrow)*D_;              \
    half8 qh[4], ql[4];                                                     \
    _Pragma("unroll")                                                       \
    for (int ks2 = 0; ks2 < 4; ++ks2) {                                     \
        const float* p = qp + ks2*32 + lg*8;                                \
        float4 v0 = *(const float4*)p;                                      \
        float4 v1 = *(const float4*)(p+4);                                  \
        float f[8] = {v0.x,v0.y,v0.z,v0.w,v1.x,v1.y,v1.z,v1.w};             \
        _Pragma("unroll")                                                   \
        for (int e = 0; e < 8; ++e) {                                       \
            _Float16 hi = (_Float16)f[e];                                   \
            _Float16 lo = (_Float16)(f[e] - (float)hi);                     \
            qh[ks2][e] = hi; ql[ks2][e] = lo;                               \
        }                                                                   \
    }

// ---------------------------------------------------------------------------
// Kernel A: l[q] = sum_k exp(s_qk)  (fixed shift 0 — overflow-safe, scores
// are ~N(0,1); mathematically identical to max-subtracted softmax denom).
// Block = (qb, ks, h, b): 128 queries x 1024 keys. Per-lane accumulate,
// one shuffle reduce at the end. Partial over ks -> lpart[b,h,q,ks].
// ---------------------------------------------------------------------------
__global__ __launch_bounds__(512) void lsum_kernel(
    const float* __restrict__ q_w, const _Float16* __restrict__ Khw,
    const _Float16* __restrict__ Klw, float* __restrict__ lpart)
{
    __shared__ __align__(16) _Float16 sKh[TB*D_];
    __shared__ __align__(16) _Float16 sKl[TB*D_];
    const int tid = threadIdx.x, wid = tid >> 6, lane = tid & 63;
    const int lg = lane >> 4, li = lane & 15;
    const int qb = blockIdx.x & 3, ks = blockIdx.x >> 2;
    const int h = blockIdx.y, b = blockIdx.z;

    const int qrow = qb*QB + wid*16 + li;
    LOAD_Q();
    const size_t kvoff = ((size_t)b*KVH_ + (h>>2)) * ((size_t)T_*D_);
    const int kt0 = ks*NTT;

    float lacc[4] = {0.f,0.f,0.f,0.f};
    STAGE(0);
    for (int tt = 0; tt < NTT; ++tt) {
        __syncthreads();
        f32x4 acc[4];
        COMPUTE_S(acc);
#pragma unroll
        for (int j = 0; j < 4; ++j)
            lacc[j] += __expf(acc[0][j]*SCALE) + __expf(acc[1][j]*SCALE)
                     + __expf(acc[2][j]*SCALE) + __expf(acc[3][j]*SCALE);
        __syncthreads();
        if (tt+1 < NTT) STAGE(tt+1);
    }
#pragma unroll
    for (int j = 0; j < 4; ++j) {
        float v = lacc[j];
        v += __shfl_xor(v, 1); v += __shfl_xor(v, 2);
        v += __shfl_xor(v, 4); v += __shfl_xor(v, 8);
        if (li == 0) {
            int q = qb*QB + wid*16 + lg*4 + j;
            lpart[(((size_t)b*H_ + h)*W_ + q)*NKS + ks] = v;
        }
    }
}

// ---------------------------------------------------------------------------
// Kernel B: bins[key] = sum_q exp(s_qk)/l_q for this block's 128 queries.
// Deterministic cross-wave merge via ping-pong LDS buffer, overlapped.
// ---------------------------------------------------------------------------
__global__ __launch_bounds__(512) void bins_kernel(
    const float* __restrict__ q_w, const _Float16* __restrict__ Khw,
    const _Float16* __restrict__ Klw, const float* __restrict__ lpart,
    float* __restrict__ partial)
{
    __shared__ __align__(16) _Float16 sKh[TB*D_];
    __shared__ __align__(16) _Float16 sKl[TB*D_];
    __shared__ float sTmp[2][512];
    const int tid = threadIdx.x, wid = tid >> 6, lane = tid & 63;
    const int lg = lane >> 4, li = lane & 15;
    const int qb = blockIdx.x & 3, ks = blockIdx.x >> 2;
    const int h = blockIdx.y, b = blockIdx.z;

    const int qrow = qb*QB + wid*16 + li;
    LOAD_Q();
    const size_t kvoff = ((size_t)b*KVH_ + (h>>2)) * ((size_t)T_*D_);
    const int kt0 = ks*NTT;

    float rv[4];
#pragma unroll
    for (int j = 0; j < 4; ++j) {
        size_t base = (((size_t)b*H_ + h)*W_ + qb*QB + wid*16 + lg*4 + j)*NKS;
        rv[j] = 1.0f/(lpart[base] + lpart[base+1] + lpart[base+2] + lpart[base+3]);
    }
    const size_t po = (((size_t)(h*NQB + qb))*B_ + b)*T_ + (size_t)ks*(NTT*TB);

    STAGE(0);
    for (int tt = 0; tt < NTT; ++tt) {
        __syncthreads();
        f32x4 acc[4];
        COMPUTE_S(acc);
#pragma unroll
        for (int n = 0; n < 4; ++n) {
            float x = __expf(acc[n][0]*SCALE)*rv[0] + __expf(acc[n][1]*SCALE)*rv[1]
                    + __expf(acc[n][2]*SCALE)*rv[2] + __expf(acc[n][3]*SCALE)*rv[3];
            x += __shfl_xor(x, 16); x += __shfl_xor(x, 32);
            if (lg == 0) sTmp[tt & 1][wid*64 + n*16 + li] = x;
        }
        if (tt > 0 && tid < 64) {
            float s = 0.f;
#pragma unroll
            for (int w = 0; w < 8; ++w) s += sTmp[(tt-1) & 1][w*64 + tid];
            partial[po + (size_t)(tt-1)*64 + tid] = s;
        }
        __syncthreads();
        if (tt+1 < NTT) STAGE(tt+1);
    }
    if (tid < 64) {
        float s = 0.f;
#pragma unroll
        for (int w = 0; w < 8; ++w) s += sTmp[(NTT-1) & 1][w*64 + tid];
        partial[po + (size_t)(NTT-1)*64 + tid] = s;
    }
}

// ---------------------------------------------------------------------------
// Kernel 2: deterministic fixed-order reduce over 128 partial slices, /H.
// ---------------------------------------------------------------------------
__global__ __launch_bounds__(256) void imp_reduce_kernel(
    const float* __restrict__ partial, float* __restrict__ imp)
{
    int gid = blockIdx.x*256 + threadIdx.x;   // 8192 = B*T
    int b = gid >> 12, t = gid & (T_-1);
    float s = 0.f;
    for (int i = 0; i < NPART; ++i)
        s += partial[((size_t)(i*B_ + b))*T_ + t];
    imp[gid] = s * (1.0f/H_);
}

// ---------------------------------------------------------------------------
// Kernel 3: per-batch bitonic top-k (desc, idx-asc tiebreak) + prefix scan.
// ---------------------------------------------------------------------------
__global__ __launch_bounds__(1024) void topk_kernel(
    const float* __restrict__ imp, int* __restrict__ mask, int* __restrict__ start)
{
    __shared__ float sv[T_];
    __shared__ int   si[T_];
    __shared__ int   sm[T_];
    __shared__ int   sa[1024], sb[1024];
    const int tid = threadIdx.x, b = blockIdx.x;

    for (int i = tid; i < T_; i += 1024) { sv[i] = imp[b*T_+i]; si[i] = i; }
    __syncthreads();

    for (int k = 2; k <= T_; k <<= 1) {
        for (int j = k >> 1; j > 0; j >>= 1) {
            for (int i = tid; i < T_; i += 1024) {
                int ix = i ^ j;
                if (ix > i) {
                    float av = sv[i], bv = sv[ix];
                    int   ai = si[i], bi = si[ix];
                    bool aFirst = (av > bv) || (av == bv && ai < bi);
                    bool desc = ((i & k) == 0);
                    if (desc ? !aFirst : aFirst) {
                        sv[i] = bv; sv[ix] = av; si[i] = bi; si[ix] = ai;
                    }
                }
            }
            __syncthreads();
        }
    }

    for (int i = tid; i < T_; i += 1024) sm[i] = 0;
    __syncthreads();
    if (tid < KTOP) sm[si[tid]] = 1;
    __syncthreads();

    int i0 = 4*tid;
    int m0 = sm[i0], m1 = sm[i0+1], m2 = sm[i0+2], m3 = sm[i0+3];
    int s4 = m0+m1+m2+m3;
    sa[tid] = s4;
    __syncthreads();
    int *src = sa, *dst = sb;
    for (int off = 1; off < 1024; off <<= 1) {
        int v = src[tid];
        if (tid >= off) v += src[tid-off];
        dst[tid] = v;
        __syncthreads();
        int* tmp = src; src = dst; dst = tmp;
    }
    int excl = src[tid] - s4;
    start[b*T_+i0+0] = i0+0 + excl;
    start[b*T_+i0+1] = i0+1 + excl + m0;
    start[b*T_+i0+2] = i0+2 + excl + m0+m1;
    start[b*T_+i0+3] = i0+3 + excl + m0+m1+m2;
    mask[b*T_+i0+0] = m0; mask[b*T_+i0+1] = m1;
    mask[b*T_+i0+2] = m2; mask[b*T_+i0+3] = m3;
}

// ---------------------------------------------------------------------------
// Kernel 4: scatter-copy rows. Every output row written exactly once.
// ---------------------------------------------------------------------------
__global__ __launch_bounds__(256) void scatter_kernel(
    const float* __restrict__ x_m, const float* __restrict__ xm_cmp,
    const int* __restrict__ mask, const int* __restrict__ start,
    float* __restrict__ out)
{
    const int t = blockIdx.x, b = blockIdx.y, tid = threadIdx.x;
    const int mk = mask[b*T_+t];
    const int st = start[b*T_+t];
    const float* s1 = mk ? (x_m + ((size_t)b*2*T_ + 2*t)*C_)
                         : (xm_cmp + ((size_t)b*T_ + t)*C_);
    float4* d1 = (float4*)(out + ((size_t)b*TOUT + st)*C_);
    const float4* s1v = (const float4*)s1;
    for (int i = tid; i < C_/4; i += 256) d1[i] = s1v[i];
    if (mk) {
        const float4* s2v = (const float4*)(x_m + ((size_t)b*2*T_ + 2*t+1)*C_);
        float4* d2 = d1 + C_/4;
        for (int i = tid; i < C_/4; i += 256) d2[i] = s2v[i];
    }
}

extern "C" void kernel_launch(void* const* d_in, const int* in_sizes, int n_in,
                              void* d_out, int out_size, void* d_ws, size_t ws_size,
                              hipStream_t stream)
{
    (void)in_sizes; (void)n_in; (void)out_size; (void)ws_size;
    const float* x_m    = (const float*)d_in[0];
    const float* xm_cmp = (const float*)d_in[1];
    const float* q_w    = (const float*)d_in[2];
    const float* km     = (const float*)d_in[3];
    float* out = (float*)d_out;

    char* ws = (char*)d_ws;
    _Float16* Khw   = (_Float16*)ws;                              // 16 MB
    _Float16* Klw   = (_Float16*)(ws + 16777216);                 // 16 MB
    float* partial  = (float*)(ws + 33554432);                    // 4 MB
    float* lpart    = (float*)(ws + 37748736);                    // 512 KB
    float* imp      = (float*)(ws + 38273024);                    // 32 KB
    int*   mask     = (int*)  (ws + 38305792);                    // 32 KB
    int*   start    = (int*)  (ws + 38338560);                    // 32 KB

    convert_k_kernel<<<dim3(4096), dim3(256), 0, stream>>>(km, Khw, Klw);
    lsum_kernel<<<dim3(NQB*NKS, H_, B_), dim3(512), 0, stream>>>(q_w, Khw, Klw, lpart);
    bins_kernel<<<dim3(NQB*NKS, H_, B_), dim3(512), 0, stream>>>(q_w, Khw, Klw, lpart, partial);
    imp_reduce_kernel<<<dim3((B_*T_)/256), dim3(256), 0, stream>>>(partial, imp);
    topk_kernel<<<dim3(B_), dim3(1024), 0, stream>>>(imp, mask, start);
    scatter_kernel<<<dim3(T_, B_), dim3(256), 0, stream>>>(x_m, xm_cmp, mask, start, out);
}